// Round 1
// baseline (610.156 us; speedup 1.0000x reference)
//
#include <hip/hip_runtime.h>

#define F 128

// ---------------- degree histogram ----------------
__global__ void deg_kernel(const int* __restrict__ src, const int* __restrict__ dst,
                           unsigned int* __restrict__ deg_out,
                           unsigned int* __restrict__ deg_in, int E) {
    int e = blockIdx.x * blockDim.x + threadIdx.x;
    if (e < E) {
        atomicAdd(&deg_out[src[e]], 1u);
        atomicAdd(&deg_in[dst[e]], 1u);
    }
}

// ---------------- norms ----------------
__global__ void norm_kernel(const unsigned int* __restrict__ deg_out,
                            const unsigned int* __restrict__ deg_in,
                            float* __restrict__ norm_src, float* __restrict__ norm_dst, int n) {
    int i = blockIdx.x * blockDim.x + threadIdx.x;
    if (i < n) {
        unsigned int dco = deg_out[i]; if (dco < 1u) dco = 1u;
        unsigned int dci = deg_in[i];  if (dci < 1u) dci = 1u;
        norm_src[i] = rsqrtf((float)dco);
        norm_dst[i] = rsqrtf((float)dci);
    }
}

// ---------------- scatter-aggregate: agg[dst] += feat[src] * norm_src[src] ----------------
// one wave (64 lanes) per edge, float2 per lane = 512B row
__global__ void scatter_kernel(const float* __restrict__ feat, const int* __restrict__ src,
                               const int* __restrict__ dst, const float* __restrict__ norm_src,
                               float* __restrict__ agg, int E) {
    int e = blockIdx.x * (blockDim.x >> 6) + (threadIdx.x >> 6);
    int lane = threadIdx.x & 63;
    if (e >= E) return;
    int s = src[e];
    int d = dst[e];
    float ns = norm_src[s];
    float2 v = ((const float2*)feat)[(size_t)s * 64 + lane];
    float* o = agg + (size_t)d * F + lane * 2;
    atomicAdd(o,     v.x * ns);
    atomicAdd(o + 1, v.y * ns);
}

// ---------------- out = relu(norm_dst[i] * (agg @ W) + b) ----------------
#define ROWS 32
__launch_bounds__(256)
__global__ void gemm_kernel(const float* __restrict__ agg, const float* __restrict__ Wg,
                            const float* __restrict__ bias, const float* __restrict__ norm_dst,
                            float* __restrict__ out, int n) {
    __shared__ float WL[128 * 128];   // 64 KB
    __shared__ float AL[ROWS * 128];  // 16 KB
    int t = threadIdx.x;

    // stage W (row-major [k][j])
    for (int i = t * 4; i < 128 * 128; i += 256 * 4)
        *(float4*)&WL[i] = *(const float4*)&Wg[i];

    int rowBase = blockIdx.x * ROWS;
    for (int i = t * 4; i < ROWS * 128; i += 256 * 4) {
        int r = rowBase + i / 128;
        if (r < n)
            *(float4*)&AL[i] = *(const float4*)&agg[(size_t)r * 128 + (i % 128)];
        else
            *(float4*)&AL[i] = make_float4(0.f, 0.f, 0.f, 0.f);
    }
    __syncthreads();

    int lane = t & 63;
    int rg = t >> 6;        // wave id 0..3 -> rows rg*8 .. rg*8+7
    int c = lane * 2;       // column pair

    float acc[8][2];
    #pragma unroll
    for (int r = 0; r < 8; r++) { acc[r][0] = 0.f; acc[r][1] = 0.f; }

    for (int k0 = 0; k0 < 128; k0 += 4) {
        float4 a4[8];
        #pragma unroll
        for (int r = 0; r < 8; r++)
            a4[r] = *(float4*)&AL[(rg * 8 + r) * 128 + k0];
        #pragma unroll
        for (int kk = 0; kk < 4; kk++) {
            float2 w2 = *(float2*)&WL[(k0 + kk) * 128 + c];
            #pragma unroll
            for (int r = 0; r < 8; r++) {
                float a = ((float*)&a4[r])[kk];
                acc[r][0] = fmaf(a, w2.x, acc[r][0]);
                acc[r][1] = fmaf(a, w2.y, acc[r][1]);
            }
        }
    }

    float b0 = bias[c], b1 = bias[c + 1];
    #pragma unroll
    for (int r = 0; r < 8; r++) {
        int row = rowBase + rg * 8 + r;
        if (row < n) {
            float nd = norm_dst[row];
            float o0 = fmaxf(fmaf(acc[r][0], nd, b0), 0.f);
            float o1 = fmaxf(fmaf(acc[r][1], nd, b1), 0.f);
            *(float2*)&out[(size_t)row * 128 + c] = make_float2(o0, o1);
        }
    }
}

extern "C" void kernel_launch(void* const* d_in, const int* in_sizes, int n_in,
                              void* d_out, int out_size, void* d_ws, size_t ws_size,
                              hipStream_t stream) {
    const float* feat = (const float*)d_in[0];
    const int*   src  = (const int*)d_in[1];
    const int*   dst  = (const int*)d_in[2];
    const float* W    = (const float*)d_in[3];
    const float* bias = (const float*)d_in[4];
    float* out = (float*)d_out;

    const int n = in_sizes[0] / F;   // 50000
    const int E = in_sizes[1];       // 600000

    char* ws = (char*)d_ws;
    unsigned int* deg_out = (unsigned int*)ws;          // n u32
    unsigned int* deg_in  = deg_out + n;                // n u32
    float* norm_src = (float*)(deg_in + n);             // n f32
    float* norm_dst = norm_src + n;                     // n f32
    float* agg = norm_dst + n;                          // n*F f32 (offset 800000 B, 16B-aligned)

    hipMemsetAsync(deg_out, 0, (size_t)2 * n * sizeof(unsigned int), stream);
    hipMemsetAsync(agg, 0, (size_t)n * F * sizeof(float), stream);

    deg_kernel<<<(E + 255) / 256, 256, 0, stream>>>(src, dst, deg_out, deg_in, E);
    norm_kernel<<<(n + 255) / 256, 256, 0, stream>>>(deg_out, deg_in, norm_src, norm_dst, n);
    scatter_kernel<<<(E + 3) / 4, 256, 0, stream>>>(feat, src, dst, norm_src, agg, E);
    gemm_kernel<<<(n + ROWS - 1) / ROWS, 256, 0, stream>>>(agg, W, bias, norm_dst, out, n);
}

// Round 2
// 200.454 us; speedup vs baseline: 3.0439x; 3.0439x over previous
//
#include <hip/hip_runtime.h>

#define F 128

// ---------------- degree histogram ----------------
__global__ void deg_kernel(const int* __restrict__ src, const int* __restrict__ dst,
                           unsigned int* __restrict__ deg_out,
                           unsigned int* __restrict__ deg_in, int E) {
    int e = blockIdx.x * blockDim.x + threadIdx.x;
    if (e < E) {
        atomicAdd(&deg_out[src[e]], 1u);
        atomicAdd(&deg_in[dst[e]], 1u);
    }
}

// ---------------- norms ----------------
__global__ void norm_kernel(const unsigned int* __restrict__ deg_out,
                            const unsigned int* __restrict__ deg_in,
                            float* __restrict__ norm_src, float* __restrict__ norm_dst, int n) {
    int i = blockIdx.x * blockDim.x + threadIdx.x;
    if (i < n) {
        unsigned int dco = deg_out[i]; if (dco < 1u) dco = 1u;
        unsigned int dci = deg_in[i];  if (dci < 1u) dci = 1u;
        norm_src[i] = rsqrtf((float)dco);
        norm_dst[i] = rsqrtf((float)dci);
    }
}

// ---------------- scan pass 1: per-block (1024-elem) sums of deg_in ----------------
__global__ void blocksum_kernel(const unsigned int* __restrict__ deg_in,
                                int* __restrict__ bsum, int n) {
    int t = threadIdx.x;
    int i0 = blockIdx.x * 1024 + t * 4;
    int s = 0;
    #pragma unroll
    for (int j = 0; j < 4; j++) {
        int i = i0 + j;
        if (i < n) s += (int)deg_in[i];
    }
    // wave reduce
    for (int off = 32; off > 0; off >>= 1) s += __shfl_down(s, off, 64);
    __shared__ int wsum[4];
    int lane = t & 63, wid = t >> 6;
    if (lane == 0) wsum[wid] = s;
    __syncthreads();
    if (t == 0) bsum[blockIdx.x] = wsum[0] + wsum[1] + wsum[2] + wsum[3];
}

// ---------------- scan pass 2: exclusive scan of block sums (nb <= 256) ----------------
__global__ void scan_bsum_kernel(int* __restrict__ bsum, unsigned int* __restrict__ row_start,
                                 int nb, int n) {
    __shared__ int sh[256];
    int t = threadIdx.x;
    int x = (t < nb) ? bsum[t] : 0;
    sh[t] = x;
    __syncthreads();
    for (int off = 1; off < 256; off <<= 1) {
        int y = (t >= off) ? sh[t - off] : 0;
        __syncthreads();
        sh[t] += y;
        __syncthreads();
    }
    if (t < nb) bsum[t] = sh[t] - x;     // exclusive
    if (t == 255) row_start[n] = (unsigned int)sh[255];  // total = E
}

// ---------------- scan pass 3: full exclusive scan -> row_start ----------------
__global__ void scan_final_kernel(const unsigned int* __restrict__ deg_in,
                                  const int* __restrict__ bsum,
                                  unsigned int* __restrict__ row_start, int n) {
    int t = threadIdx.x;
    int lane = t & 63, wid = t >> 6;
    int i0 = blockIdx.x * 1024 + t * 4;
    int v0 = 0, v1 = 0, v2 = 0, v3 = 0;
    if (i0 + 0 < n) v0 = (int)deg_in[i0 + 0];
    if (i0 + 1 < n) v1 = (int)deg_in[i0 + 1];
    if (i0 + 2 < n) v2 = (int)deg_in[i0 + 2];
    if (i0 + 3 < n) v3 = (int)deg_in[i0 + 3];
    int sum4 = v0 + v1 + v2 + v3;
    // wave inclusive scan of sum4
    int x = sum4;
    for (int off = 1; off < 64; off <<= 1) {
        int y = __shfl_up(x, off, 64);
        if (lane >= off) x += y;
    }
    int wex = x - sum4;  // wave-exclusive
    __shared__ int wtot[4];
    if (lane == 63) wtot[wid] = x;
    __syncthreads();
    int wbase = 0;
    for (int w = 0; w < wid; w++) wbase += wtot[w];
    int base = bsum[blockIdx.x] + wbase + wex;
    if (i0 + 0 < n) row_start[i0 + 0] = (unsigned int)(base);
    if (i0 + 1 < n) row_start[i0 + 1] = (unsigned int)(base + v0);
    if (i0 + 2 < n) row_start[i0 + 2] = (unsigned int)(base + v0 + v1);
    if (i0 + 3 < n) row_start[i0 + 3] = (unsigned int)(base + v0 + v1 + v2);
}

// ---------------- placement: bucket edge sources by dst ----------------
__global__ void place_kernel(const int* __restrict__ src, const int* __restrict__ dst,
                             const unsigned int* __restrict__ row_start,
                             unsigned int* __restrict__ cursor,
                             int* __restrict__ eidx, int E) {
    int e = blockIdx.x * blockDim.x + threadIdx.x;
    if (e < E) {
        int d = dst[e];
        unsigned int pos = row_start[d] + atomicAdd(&cursor[d], 1u);
        eidx[pos] = src[e];
    }
}

// ---------------- gather-reduce: agg[d] = norm_dst[d] * sum_{s in N(d)} feat[s]*norm_src[s] ----------------
// one wave per dst row, float2 per lane
__global__ void gather_kernel(const float2* __restrict__ feat2, const int* __restrict__ eidx,
                              const unsigned int* __restrict__ row_start,
                              const float* __restrict__ norm_src,
                              const float* __restrict__ norm_dst,
                              float2* __restrict__ agg2, int n) {
    int d = blockIdx.x * (blockDim.x >> 6) + (threadIdx.x >> 6);
    if (d >= n) return;
    int lane = threadIdx.x & 63;
    int beg = (int)row_start[d], end = (int)row_start[d + 1];
    float ax = 0.f, ay = 0.f;
    int k = beg;
    for (; k + 2 <= end; k += 2) {
        int s0 = __builtin_amdgcn_readfirstlane(eidx[k]);
        int s1 = __builtin_amdgcn_readfirstlane(eidx[k + 1]);
        float ns0 = norm_src[s0];
        float ns1 = norm_src[s1];
        float2 v0 = feat2[(size_t)s0 * 64 + lane];
        float2 v1 = feat2[(size_t)s1 * 64 + lane];
        ax = fmaf(v0.x, ns0, ax); ay = fmaf(v0.y, ns0, ay);
        ax = fmaf(v1.x, ns1, ax); ay = fmaf(v1.y, ns1, ay);
    }
    if (k < end) {
        int s0 = __builtin_amdgcn_readfirstlane(eidx[k]);
        float ns0 = norm_src[s0];
        float2 v0 = feat2[(size_t)s0 * 64 + lane];
        ax = fmaf(v0.x, ns0, ax); ay = fmaf(v0.y, ns0, ay);
    }
    float nd = norm_dst[d];
    agg2[(size_t)d * 64 + lane] = make_float2(ax * nd, ay * nd);
}

// ---------------- out = relu(agg @ W + b) ----------------
#define ROWS 32
__launch_bounds__(256)
__global__ void gemm_kernel(const float* __restrict__ agg, const float* __restrict__ Wg,
                            const float* __restrict__ bias,
                            float* __restrict__ out, int n) {
    __shared__ float WL[128 * 128];   // 64 KB
    __shared__ float AL[ROWS * 128];  // 16 KB
    int t = threadIdx.x;

    for (int i = t * 4; i < 128 * 128; i += 256 * 4)
        *(float4*)&WL[i] = *(const float4*)&Wg[i];

    int rowBase = blockIdx.x * ROWS;
    for (int i = t * 4; i < ROWS * 128; i += 256 * 4) {
        int r = rowBase + i / 128;
        if (r < n)
            *(float4*)&AL[i] = *(const float4*)&agg[(size_t)r * 128 + (i % 128)];
        else
            *(float4*)&AL[i] = make_float4(0.f, 0.f, 0.f, 0.f);
    }
    __syncthreads();

    int lane = t & 63;
    int rg = t >> 6;
    int c = lane * 2;

    float acc[8][2];
    #pragma unroll
    for (int r = 0; r < 8; r++) { acc[r][0] = 0.f; acc[r][1] = 0.f; }

    for (int k0 = 0; k0 < 128; k0 += 4) {
        float4 a4[8];
        #pragma unroll
        for (int r = 0; r < 8; r++)
            a4[r] = *(float4*)&AL[(rg * 8 + r) * 128 + k0];
        #pragma unroll
        for (int kk = 0; kk < 4; kk++) {
            float2 w2 = *(float2*)&WL[(k0 + kk) * 128 + c];
            #pragma unroll
            for (int r = 0; r < 8; r++) {
                float a = ((float*)&a4[r])[kk];
                acc[r][0] = fmaf(a, w2.x, acc[r][0]);
                acc[r][1] = fmaf(a, w2.y, acc[r][1]);
            }
        }
    }

    float b0 = bias[c], b1 = bias[c + 1];
    #pragma unroll
    for (int r = 0; r < 8; r++) {
        int row = rowBase + rg * 8 + r;
        if (row < n) {
            float o0 = fmaxf(acc[r][0] + b0, 0.f);
            float o1 = fmaxf(acc[r][1] + b1, 0.f);
            *(float2*)&out[(size_t)row * 128 + c] = make_float2(o0, o1);
        }
    }
}

extern "C" void kernel_launch(void* const* d_in, const int* in_sizes, int n_in,
                              void* d_out, int out_size, void* d_ws, size_t ws_size,
                              hipStream_t stream) {
    const float* feat = (const float*)d_in[0];
    const int*   src  = (const int*)d_in[1];
    const int*   dst  = (const int*)d_in[2];
    const float* W    = (const float*)d_in[3];
    const float* bias = (const float*)d_in[4];
    float* out = (float*)d_out;

    const int n = in_sizes[0] / F;   // 50000
    const int E = in_sizes[1];       // 600000
    const int nb = (n + 1023) / 1024;

    char* p = (char*)d_ws;
    auto alloc = [&](size_t bytes) { char* r = p; p += (bytes + 255) & ~255ull; return r; };
    unsigned int* deg_out   = (unsigned int*)alloc((size_t)n * 4);
    unsigned int* deg_in    = (unsigned int*)alloc((size_t)n * 4);
    float*        norm_src  = (float*)alloc((size_t)n * 4);
    float*        norm_dst  = (float*)alloc((size_t)n * 4);
    unsigned int* row_start = (unsigned int*)alloc((size_t)(n + 1) * 4);
    unsigned int* cursor    = (unsigned int*)alloc((size_t)n * 4);
    int*          bsum      = (int*)alloc(256 * 4);
    int*          eidx      = (int*)alloc((size_t)E * 4);
    float*        agg       = (float*)alloc((size_t)n * F * 4);

    hipMemsetAsync(deg_out, 0, (size_t)2 * n * 4, stream);   // deg_out + deg_in (contiguous-ish: separate allocs may pad; do separately)
    hipMemsetAsync(deg_in, 0, (size_t)n * 4, stream);
    hipMemsetAsync(cursor, 0, (size_t)n * 4, stream);

    deg_kernel<<<(E + 255) / 256, 256, 0, stream>>>(src, dst, deg_out, deg_in, E);
    norm_kernel<<<(n + 255) / 256, 256, 0, stream>>>(deg_out, deg_in, norm_src, norm_dst, n);
    blocksum_kernel<<<nb, 256, 0, stream>>>(deg_in, bsum, n);
    scan_bsum_kernel<<<1, 256, 0, stream>>>(bsum, row_start, nb, n);
    scan_final_kernel<<<nb, 256, 0, stream>>>(deg_in, bsum, row_start, n);
    place_kernel<<<(E + 255) / 256, 256, 0, stream>>>(src, dst, row_start, cursor, eidx, E);
    gather_kernel<<<(n + 3) / 4, 256, 0, stream>>>((const float2*)feat, eidx, row_start,
                                                   norm_src, norm_dst, (float2*)agg, n);
    gemm_kernel<<<(n + ROWS - 1) / ROWS, 256, 0, stream>>>(agg, W, bias, out, n);
}

// Round 4
// 150.727 us; speedup vs baseline: 4.0481x; 1.3299x over previous
//
#include <hip/hip_runtime.h>
#include <hip/hip_bf16.h>

#define F 128

typedef unsigned int u32;
typedef unsigned short u16;
typedef __attribute__((ext_vector_type(8))) short short8;   // bf16x8 MFMA frag
typedef __attribute__((ext_vector_type(4))) float f32x4;    // MFMA acc

__device__ __forceinline__ u16 f2bf(float x) {
    u32 u = __float_as_uint(x);
    u32 r = u + 0x7fffu + ((u >> 16) & 1u);   // RNE
    return (u16)(r >> 16);
}

// ---------------- degree histogram ----------------
__global__ void deg_kernel(const int* __restrict__ src, const int* __restrict__ dst,
                           u32* __restrict__ deg_out, u32* __restrict__ deg_in, int E) {
    int e = blockIdx.x * blockDim.x + threadIdx.x;
    if (e < E) {
        atomicAdd(&deg_out[src[e]], 1u);
        atomicAdd(&deg_in[dst[e]], 1u);
    }
}

// ---------------- xb = bf16(feat * rsqrt(max(deg_out,1))) ----------------
__global__ void xconv_kernel(const float4* __restrict__ feat4, const u32* __restrict__ deg_out,
                             ushort4* __restrict__ xb4, int total) {  // total = n*32
    int i = blockIdx.x * blockDim.x + threadIdx.x;
    if (i >= total) return;
    int row = i >> 5;
    u32 dg = deg_out[row]; if (dg < 1u) dg = 1u;
    float ns = rsqrtf((float)dg);
    float4 v = feat4[i];
    ushort4 o;
    o.x = f2bf(v.x * ns); o.y = f2bf(v.y * ns);
    o.z = f2bf(v.z * ns); o.w = f2bf(v.w * ns);
    xb4[i] = o;
}

// ---------------- W -> bf16, transposed [col][k], XOR-swizzled 16B granules ----------------
__global__ void wconv_kernel(const float* __restrict__ Wg, u16* __restrict__ wsw) {
    int i = blockIdx.x * blockDim.x + threadIdx.x;  // 0..16383
    int k = i >> 7, col = i & 127;
    u16 h = f2bf(Wg[i]);                            // Wg row-major [k][col]
    // u16 index: col*128 + swizzled position of k
    wsw[col * 128 + 8 * ((k >> 3) ^ (col & 15)) + (k & 7)] = h;
}

// ---------------- scan pass 1: per-1024 block sums of deg_in ----------------
__global__ void blocksum_kernel(const u32* __restrict__ deg_in, int* __restrict__ bsum, int n) {
    int t = threadIdx.x;
    int i0 = blockIdx.x * 1024 + t * 4;
    int s = 0;
    #pragma unroll
    for (int j = 0; j < 4; j++) { int i = i0 + j; if (i < n) s += (int)deg_in[i]; }
    for (int off = 32; off > 0; off >>= 1) s += __shfl_down(s, off, 64);
    __shared__ int wsum[4];
    int lane = t & 63, wid = t >> 6;
    if (lane == 0) wsum[wid] = s;
    __syncthreads();
    if (t == 0) bsum[blockIdx.x] = wsum[0] + wsum[1] + wsum[2] + wsum[3];
}

// ---------------- scan pass 2: exclusive scan of block sums (nb <= 256) ----------------
__global__ void scan_bsum_kernel(int* __restrict__ bsum, u32* __restrict__ row_start,
                                 int nb, int n) {
    __shared__ int sh[256];
    int t = threadIdx.x;
    int x = (t < nb) ? bsum[t] : 0;
    sh[t] = x;
    __syncthreads();
    for (int off = 1; off < 256; off <<= 1) {
        int y = (t >= off) ? sh[t - off] : 0;
        __syncthreads();
        sh[t] += y;
        __syncthreads();
    }
    if (t < nb) bsum[t] = sh[t] - x;
    if (t == 255) row_start[n] = (u32)sh[255];
}

// ---------------- scan pass 3: full exclusive scan -> row_start ----------------
__global__ void scan_final_kernel(const u32* __restrict__ deg_in, const int* __restrict__ bsum,
                                  u32* __restrict__ row_start, int n) {
    int t = threadIdx.x;
    int lane = t & 63, wid = t >> 6;
    int i0 = blockIdx.x * 1024 + t * 4;
    int v0 = 0, v1 = 0, v2 = 0, v3 = 0;
    if (i0 + 0 < n) v0 = (int)deg_in[i0 + 0];
    if (i0 + 1 < n) v1 = (int)deg_in[i0 + 1];
    if (i0 + 2 < n) v2 = (int)deg_in[i0 + 2];
    if (i0 + 3 < n) v3 = (int)deg_in[i0 + 3];
    int sum4 = v0 + v1 + v2 + v3;
    int x = sum4;
    for (int off = 1; off < 64; off <<= 1) {
        int y = __shfl_up(x, off, 64);
        if (lane >= off) x += y;
    }
    int wex = x - sum4;
    __shared__ int wtot[4];
    if (lane == 63) wtot[wid] = x;
    __syncthreads();
    int wbase = 0;
    for (int w = 0; w < wid; w++) wbase += wtot[w];
    int base = bsum[blockIdx.x] + wbase + wex;
    if (i0 + 0 < n) row_start[i0 + 0] = (u32)(base);
    if (i0 + 1 < n) row_start[i0 + 1] = (u32)(base + v0);
    if (i0 + 2 < n) row_start[i0 + 2] = (u32)(base + v0 + v1);
    if (i0 + 3 < n) row_start[i0 + 3] = (u32)(base + v0 + v1 + v2);
}

// ---------------- placement: bucket edge sources by dst ----------------
__global__ void place_kernel(const int* __restrict__ src, const int* __restrict__ dst,
                             const u32* __restrict__ row_start, u32* __restrict__ cursor,
                             int* __restrict__ eidx, int E) {
    int e = blockIdx.x * blockDim.x + threadIdx.x;
    if (e < E) {
        int d = dst[e];
        u32 pos = row_start[d] + atomicAdd(&cursor[d], 1u);
        eidx[pos] = src[e];
    }
}

// ---------------- gather: aggb[d] = bf16( norm_dst[d] * sum xb[s] ) ----------------
// one wave per dst row; lane holds one u32 (2 bf16)
__global__ void gather_kernel(const u32* __restrict__ xb32, const int* __restrict__ eidx,
                              const u32* __restrict__ row_start, const u32* __restrict__ deg_in,
                              u32* __restrict__ aggb32, int n) {
    int d = blockIdx.x * (blockDim.x >> 6) + (threadIdx.x >> 6);
    if (d >= n) return;
    int lane = threadIdx.x & 63;
    int beg = (int)row_start[d], end = (int)row_start[d + 1];
    float ax = 0.f, ay = 0.f;
    int k = beg;
    for (; k + 4 <= end; k += 4) {
        int s0 = __builtin_amdgcn_readfirstlane(eidx[k + 0]);
        int s1 = __builtin_amdgcn_readfirstlane(eidx[k + 1]);
        int s2 = __builtin_amdgcn_readfirstlane(eidx[k + 2]);
        int s3 = __builtin_amdgcn_readfirstlane(eidx[k + 3]);
        u32 v0 = xb32[(size_t)s0 * 64 + lane];
        u32 v1 = xb32[(size_t)s1 * 64 + lane];
        u32 v2 = xb32[(size_t)s2 * 64 + lane];
        u32 v3 = xb32[(size_t)s3 * 64 + lane];
        ax += __uint_as_float(v0 << 16);           ay += __uint_as_float(v0 & 0xffff0000u);
        ax += __uint_as_float(v1 << 16);           ay += __uint_as_float(v1 & 0xffff0000u);
        ax += __uint_as_float(v2 << 16);           ay += __uint_as_float(v2 & 0xffff0000u);
        ax += __uint_as_float(v3 << 16);           ay += __uint_as_float(v3 & 0xffff0000u);
    }
    for (; k < end; k++) {
        int s0 = __builtin_amdgcn_readfirstlane(eidx[k]);
        u32 v0 = xb32[(size_t)s0 * 64 + lane];
        ax += __uint_as_float(v0 << 16);           ay += __uint_as_float(v0 & 0xffff0000u);
    }
    u32 dg = deg_in[d]; if (dg < 1u) dg = 1u;
    float nd = rsqrtf((float)dg);
    u32 lo = (u32)f2bf(ax * nd);
    u32 hi = (u32)f2bf(ay * nd);
    aggb32[(size_t)d * 64 + lane] = lo | (hi << 16);
}

// ---------------- out = relu(aggb @ W + b), MFMA bf16 ----------------
#define BM 64
__launch_bounds__(256)
__global__ void gemm_kernel(const u32* __restrict__ aggb, const uint4* __restrict__ wsw4,
                            const float* __restrict__ bias, float* __restrict__ out, int n) {
    __shared__ uint4 WL[2048];   // 32 KB: 128 cols x 256B (16 granules of 16B each)
    int t = threadIdx.x;
    for (int j = t; j < 2048; j += 256)
        WL[j] = wsw4[j];
    __syncthreads();

    int lane = t & 63;
    int wv = t >> 6;
    int g = lane >> 4;
    int c15 = lane & 15;

    int rowA = blockIdx.x * BM + wv * 16 + c15;
    if (rowA >= n) rowA = n - 1;                 // clamp (result discarded by store guard)
    const short8* arow = (const short8*)(aggb + (size_t)rowA * 64);  // 16 granules of 16B

    f32x4 acc[8];
    #pragma unroll
    for (int nf = 0; nf < 8; nf++) acc[nf] = (f32x4){0.f, 0.f, 0.f, 0.f};

    #pragma unroll
    for (int kk = 0; kk < 4; kk++) {
        short8 a = arow[4 * kk + g];             // k = 32kk + 8g .. +7
        int sg = (4 * kk + g) ^ c15;             // swizzled granule within col row
        #pragma unroll
        for (int nf = 0; nf < 8; nf++) {
            int col = c15 + 16 * nf;
            short8 b = ((const short8*)WL)[col * 16 + sg];
            acc[nf] = __builtin_amdgcn_mfma_f32_16x16x32_bf16(a, b, acc[nf], 0, 0, 0);
        }
    }

    int rbase = blockIdx.x * BM + wv * 16 + g * 4;   // D: row=(lane>>4)*4+r, col=lane&15 (+16nf)
    #pragma unroll
    for (int nf = 0; nf < 8; nf++) {
        int col = c15 + 16 * nf;
        float bv = bias[col];
        #pragma unroll
        for (int r = 0; r < 4; r++) {
            int row = rbase + r;
            if (row < n)
                out[(size_t)row * F + col] = fmaxf(acc[nf][r] + bv, 0.f);
        }
    }
}

extern "C" void kernel_launch(void* const* d_in, const int* in_sizes, int n_in,
                              void* d_out, int out_size, void* d_ws, size_t ws_size,
                              hipStream_t stream) {
    const float* feat = (const float*)d_in[0];
    const int*   src  = (const int*)d_in[1];
    const int*   dst  = (const int*)d_in[2];
    const float* W    = (const float*)d_in[3];
    const float* bias = (const float*)d_in[4];
    float* out = (float*)d_out;

    const int n = in_sizes[0] / F;   // 50000
    const int E = in_sizes[1];       // 600000
    const int nb = (n + 1023) / 1024;

    char* p = (char*)d_ws;
    auto alloc = [&](size_t bytes) { char* r = p; p += (bytes + 255) & ~255ull; return r; };
    u32* degs      = (u32*)alloc((size_t)3 * n * 4);   // deg_out | deg_in | cursor (one memset)
    u32* deg_out   = degs;
    u32* deg_in    = degs + n;
    u32* cursor    = degs + 2 * n;
    u32* row_start = (u32*)alloc((size_t)(n + 1) * 4);
    int* bsum      = (int*)alloc(256 * 4);
    int* eidx      = (int*)alloc((size_t)E * 4);
    u32* xb        = (u32*)alloc((size_t)n * F * 2);   // bf16 feat*norm_src
    u32* aggb      = (u32*)alloc((size_t)n * F * 2);   // bf16 aggregate
    u16* wsw       = (u16*)alloc(128 * 128 * 2);       // swizzled transposed bf16 W

    hipMemsetAsync(degs, 0, (size_t)3 * n * 4, stream);

    deg_kernel<<<(E + 255) / 256, 256, 0, stream>>>(src, dst, deg_out, deg_in, E);
    xconv_kernel<<<(n * 32 + 255) / 256, 256, 0, stream>>>((const float4*)feat, deg_out,
                                                           (ushort4*)xb, n * 32);
    wconv_kernel<<<64, 256, 0, stream>>>(W, wsw);
    blocksum_kernel<<<nb, 256, 0, stream>>>(deg_in, bsum, n);
    scan_bsum_kernel<<<1, 256, 0, stream>>>(bsum, row_start, nb, n);
    scan_final_kernel<<<nb, 256, 0, stream>>>(deg_in, bsum, row_start, n);
    place_kernel<<<(E + 255) / 256, 256, 0, stream>>>(src, dst, row_start, cursor, eidx, E);
    gather_kernel<<<(n + 3) / 4, 256, 0, stream>>>(xb, eidx, row_start, deg_in, aggb, n);
    gemm_kernel<<<(n + BM - 1) / BM, 256, 0, stream>>>(aggb, (const uint4*)wsw, bias, out, n);
}